// Round 6
// baseline (631.787 us; speedup 1.0000x reference)
//
#include <hip/hip_runtime.h>
#include <math.h>
#include <type_traits>

typedef unsigned short u16;
typedef __attribute__((ext_vector_type(8))) short bf16x8;
typedef __attribute__((ext_vector_type(4))) float f32x4;

// Problem constants (fixed by the reference)
#define B_  2
#define S_  2048
#define D_  2048
#define H_  16
#define HD_ 128
#define L_  512
constexpr float EPS   = 1e-5f;
constexpr float SCALE = 0.08838834764831845f; // 1/sqrt(128)

__device__ __forceinline__ u16 f2bf(float x) {
    unsigned u = __float_as_uint(x);
    u += 0x7fffu + ((u >> 16) & 1u);   // round-to-nearest-even
    return (u16)(u >> 16);
}
__device__ __forceinline__ float bf2f(u16 v) {
    return __uint_as_float(((unsigned)v) << 16);
}

// async global->LDS, 16 B per lane; LDS dest = lptr + lane*16 (wave-uniform base)
__device__ __forceinline__ void gl_lds16(const u16* g, u16* l) {
    __builtin_amdgcn_global_load_lds(
        (const __attribute__((address_space(1))) unsigned int*)g,
        (__attribute__((address_space(3))) unsigned int*)l, 16, 0, 0);
}

// ---------------------------------------------------------------------------
// bf16 MFMA GEMM (m97 structure): C[M,N] = A[M,K] @ Bt[N,K]^T + bias[N]
// 128x128 tile, BK=32, 256 thr, 4 waves x (64x64 via 4x4 mfma 16x16x32).
// ---------------------------------------------------------------------------
template <typename OutT>
__global__ __launch_bounds__(256)
void gemm_mfma_kernel(const u16* __restrict__ A, const u16* __restrict__ Bt,
                      const float* __restrict__ bias, OutT* __restrict__ C,
                      int M, int N, int K) {
    __shared__ __align__(16) u16 As[128 * 32];
    __shared__ __align__(16) u16 Bs[128 * 32];

    const int tid  = threadIdx.x;
    const int wave = tid >> 6, lane = tid & 63;
    const int l15  = lane & 15, g = lane >> 4;
    const int wm   = wave >> 1, wn = wave & 1;
    const int m0   = blockIdx.y * 128, n0 = blockIdx.x * 128;

    const int sr = lane >> 2;       // staging row within 16-row group
    const int sc = lane & 3;        // chunk slot
    const int swz = (l15 >> 1) & 3; // read-side swizzle key

    f32x4 acc[4][4];
#pragma unroll
    for (int i = 0; i < 4; ++i)
#pragma unroll
        for (int j = 0; j < 4; ++j) acc[i][j] = (f32x4)0.f;

    for (int k0 = 0; k0 < K; k0 += 32) {
#pragma unroll
        for (int t = 0; t < 2; ++t) {
            const int r  = wave * 32 + t * 16 + sr;
            const int c  = sc ^ ((r >> 1) & 3);
            gl_lds16(A  + (size_t)(m0 + r) * K + k0 + c * 8,
                     &As[(wave * 32 + t * 16) * 32]);
            gl_lds16(Bt + (size_t)(n0 + r) * K + k0 + c * 8,
                     &Bs[(wave * 32 + t * 16) * 32]);
        }
        __syncthreads();

        bf16x8 af[4], bfr[4];
#pragma unroll
        for (int i = 0; i < 4; ++i) {
            const int ra = wm * 64 + i * 16 + l15;
            af[i]  = *(const bf16x8*)&As[ra * 32 + (g ^ swz) * 8];
            const int rb = wn * 64 + i * 16 + l15;
            bfr[i] = *(const bf16x8*)&Bs[rb * 32 + (g ^ swz) * 8];
        }
#pragma unroll
        for (int i = 0; i < 4; ++i)
#pragma unroll
            for (int j = 0; j < 4; ++j)
                acc[i][j] = __builtin_amdgcn_mfma_f32_16x16x32_bf16(
                    af[i], bfr[j], acc[i][j], 0, 0, 0);
        __syncthreads();
    }

#pragma unroll
    for (int j = 0; j < 4; ++j) {
        const int n  = n0 + wn * 64 + j * 16 + l15;
        const float bv = bias[n];
#pragma unroll
        for (int i = 0; i < 4; ++i) {
            const int mb = m0 + wm * 64 + i * 16 + g * 4;
#pragma unroll
            for (int r = 0; r < 4; ++r) {
                float v = acc[i][j][r] + bv;
                if constexpr (std::is_same_v<OutT, float>)
                    C[(size_t)(mb + r) * N + n] = v;
                else
                    C[(size_t)(mb + r) * N + n] = f2bf(v);
            }
        }
    }
}

// ---------------------------------------------------------------------------
// fp32 -> bf16 cast
// ---------------------------------------------------------------------------
__global__ __launch_bounds__(256)
void cast_bf16_kernel(const float* __restrict__ src, u16* __restrict__ dst,
                      int n4) {
    const int i = blockIdx.x * 256 + threadIdx.x;
    if (i < n4) {
        float4 f = ((const float4*)src)[i];
        ushort4 o;
        o.x = f2bf(f.x); o.y = f2bf(f.y); o.z = f2bf(f.z); o.w = f2bf(f.w);
        ((ushort4*)dst)[i] = o;
    }
}

// ---------------------------------------------------------------------------
// fp32 W[K,N] -> bf16 Wt[N,K]
// ---------------------------------------------------------------------------
__global__ __launch_bounds__(256)
void cast_transpose_kernel(const float* __restrict__ W, u16* __restrict__ Wt,
                           int K, int N) {
    __shared__ u16 T[64][72];
    const int n0 = blockIdx.x * 64, k0 = blockIdx.y * 64;
    const int t  = threadIdx.x;
    {
        const int kr = t >> 2, nc = (t & 3) * 16;
#pragma unroll
        for (int v = 0; v < 4; ++v) {
            float4 f = *(const float4*)&W[(size_t)(k0 + kr) * N + n0 + nc + v * 4];
            T[nc + v * 4 + 0][kr] = f2bf(f.x);
            T[nc + v * 4 + 1][kr] = f2bf(f.y);
            T[nc + v * 4 + 2][kr] = f2bf(f.z);
            T[nc + v * 4 + 3][kr] = f2bf(f.w);
        }
    }
    __syncthreads();
    {
        const int nr = t >> 2, kc = (t & 3) * 16;
        union { u16 u[16]; uint4 q[2]; } o;
#pragma unroll
        for (int i = 0; i < 16; ++i) o.u[i] = T[nr][kc + i];
        uint4* dst = (uint4*)&Wt[(size_t)(n0 + nr) * K + k0 + kc];
        dst[0] = o.q[0]; dst[1] = o.q[1];
    }
}

// ---------------------------------------------------------------------------
// In-place bf16 row LayerNorm, rows of 512
// ---------------------------------------------------------------------------
__global__ __launch_bounds__(256)
void layernorm512_bf16_kernel(u16* __restrict__ buf, const float* __restrict__ g,
                              const float* __restrict__ bvec) {
    const int row = blockIdx.x;
    u16* p = buf + (size_t)row * L_;
    const int tid = threadIdx.x;

    float x0 = bf2f(p[tid]), x1 = bf2f(p[tid + 256]);
    float s  = x0 + x1;
    float sq = x0 * x0 + x1 * x1;

    __shared__ float red[8];
    __shared__ float stats[2];

#pragma unroll
    for (int off = 32; off; off >>= 1) {
        s  += __shfl_down(s, off);
        sq += __shfl_down(sq, off);
    }
    const int wave = tid >> 6;
    if ((tid & 63) == 0) { red[wave] = s; red[wave + 4] = sq; }
    __syncthreads();
    if (tid == 0) {
        float ts = red[0] + red[1] + red[2] + red[3];
        float tq = red[4] + red[5] + red[6] + red[7];
        float mean = ts / (float)L_;
        float var  = tq / (float)L_ - mean * mean;
        stats[0] = mean;
        stats[1] = rsqrtf(var + EPS);
    }
    __syncthreads();
    const float mean = stats[0], rstd = stats[1];
    p[tid]       = f2bf((x0 - mean) * rstd * g[tid]       + bvec[tid]);
    p[tid + 256] = f2bf((x1 - mean) * rstd * g[tid + 256] + bvec[tid + 256]);
}

// ---------------------------------------------------------------------------
// V transpose: vt[(b*H+h)*HD + d][s] = kv_bf[(b*S+s)*2D + D + h*HD + d]
// ---------------------------------------------------------------------------
__global__ __launch_bounds__(256)
void vtrans_kernel(const u16* __restrict__ kvbf, u16* __restrict__ vt) {
    const int s0 = blockIdx.x * 64;
    const int h  = blockIdx.y, b = blockIdx.z;
    __shared__ u16 T[64][136];
    const int t = threadIdx.x;
    {
        const int sl = t >> 2, dc = (t & 3) * 32;
        const uint4* src = (const uint4*)(kvbf +
            ((size_t)(b * S_ + s0 + sl) * (2 * D_) + D_ + h * HD_ + dc));
        uint4 a0 = src[0], a1 = src[1], a2 = src[2], a3 = src[3];
        *(uint4*)&T[sl][dc]      = a0;
        *(uint4*)&T[sl][dc + 8]  = a1;
        *(uint4*)&T[sl][dc + 16] = a2;
        *(uint4*)&T[sl][dc + 24] = a3;
    }
    __syncthreads();
    {
        const int d = t >> 1, sh = (t & 1) * 32;
        union { u16 u[32]; uint4 q[4]; } buf;
#pragma unroll
        for (int i = 0; i < 32; ++i) buf.u[i] = T[sh + i][d];
        uint4* dst = (uint4*)(vt +
            ((size_t)((b * H_ + h) * HD_ + d)) * S_ + s0 + sh);
        dst[0] = buf.q[0]; dst[1] = buf.q[1];
        dst[2] = buf.q[2]; dst[3] = buf.q[3];
    }
}

// ---------------------------------------------------------------------------
// Flash attention v4: S^T-domain softmax.
// 16 queries per wave, full causal K-range, zero barriers.
// QK^T computed as K@Q^T (operand swap; identical load addresses) so the
// C-layout puts KEYS on rows (registers) and the QUERY on col=l15. Softmax
// reductions become: in-register over 8 key-values + 2 cross-lane hops
// (xor 16, 32) instead of 2x 4-deep shuffle chains over 16 lanes.
// m/l state: one scalar per lane (q = l15). P packed as 2x ds_write_b64,
// read back in A-layout [q][key]; PV and O layout unchanged. alpha / 1/l
// move softmax-domain -> O-domain via 4 __shfl (rescale is max-change-gated).
// grid: (S/64)*H*B = 1024 blocks, heavy q-groups first.
// ---------------------------------------------------------------------------
#define PPITCH 40

__global__ __launch_bounds__(256)
void flash_attn_kernel(const u16* __restrict__ qbf, const u16* __restrict__ kvbf,
                       const u16* __restrict__ vt,
                       const unsigned char* __restrict__ mask,
                       u16* __restrict__ out) {
    const int x    = blockIdx.x;
    const int qgrp = (S_ / 64 - 1) - (x >> 5);   // heavy blocks first
    const int hb   = x & 31;
    const int h    = hb >> 1, b = hb & 1;
    const int tid  = threadIdx.x;
    const int wave = tid >> 6, lane = tid & 63;
    const int l15  = lane & 15, g = lane >> 4;
    const int q0   = qgrp * 64 + wave * 16;      // this wave's 16 queries
    const int qi   = q0 + l15;                   // softmax-domain q

    __shared__ __align__(16) u16 Pl[4][16][PPITCH];   // per-wave P slice

    // Q as B-operand: B[kk = g*8+j][col = q = l15] = Q[qi][c*32 + g*8 + j]
    bf16x8 qf[4];
#pragma unroll
    for (int c = 0; c < 4; ++c)
        qf[c] = *(const bf16x8*)(qbf +
            (size_t)(b * S_ + qi) * D_ + h * HD_ + c * 32 + g * 8);

    f32x4 o[8];
#pragma unroll
    for (int i = 0; i < 8; ++i) o[i] = (f32x4)0.f;
    float m_run = -INFINITY, l_run = 0.f;

    const u16* kbase = kvbf + (size_t)b * S_ * (2 * D_) + h * HD_;
    const u16* vbase = vt + (size_t)((b * H_ + h) * HD_) * S_;
    const unsigned char* mbase = mask + b * S_;
    const int nt = ((q0 + 15) >> 5) + 1;   // 32-key causal tiles

    for (int kt = 0; kt < nt; ++kt) {
        const int k0 = kt * 32;

        // K as A-operand: A[row = key = l15][kk] (same addresses as before)
        bf16x8 kf0[4], kf1[4];
#pragma unroll
        for (int c = 0; c < 4; ++c) {
            kf0[c] = *(const bf16x8*)(kbase +
                (size_t)(k0 + l15) * (2 * D_) + c * 32 + g * 8);
            kf1[c] = *(const bf16x8*)(kbase +
                (size_t)(k0 + 16 + l15) * (2 * D_) + c * 32 + g * 8);
        }

        // S^T tiles: rows = keys (4g+r), col = q = l15
        f32x4 s0 = (f32x4)0.f, s1 = (f32x4)0.f;
#pragma unroll
        for (int c = 0; c < 4; ++c) {
            s0 = __builtin_amdgcn_mfma_f32_16x16x32_bf16(kf0[c], qf[c], s0, 0, 0, 0);
            s1 = __builtin_amdgcn_mfma_f32_16x16x32_bf16(kf1[c], qf[c], s1, 0, 0, 0);
        }

        // scale + causal/padding mask. Lane's keys: kb0+r and kb1+r.
        const int kb0 = k0 + 4 * g, kb1 = k0 + 16 + 4 * g;
        const unsigned w0 = *(const unsigned*)(mbase + kb0);
        const unsigned w1 = *(const unsigned*)(mbase + kb1);
#pragma unroll
        for (int r = 0; r < 4; ++r) {
            float v0 = s0[r] * SCALE, v1 = s1[r] * SCALE;
            if (kb0 + r > qi || ((w0 >> (8 * r)) & 0xffu)) v0 = -INFINITY;
            if (kb1 + r > qi || ((w1 >> (8 * r)) & 0xffu)) v1 = -INFINITY;
            s0[r] = v0; s1[r] = v1;
        }

        // row max: 8 in-register values, then 2 cross-lane hops
        float tm = fmaxf(fmaxf(fmaxf(s0[0], s0[1]), fmaxf(s0[2], s0[3])),
                         fmaxf(fmaxf(s1[0], s1[1]), fmaxf(s1[2], s1[3])));
        tm = fmaxf(tm, __shfl_xor(tm, 16));
        tm = fmaxf(tm, __shfl_xor(tm, 32));

        const float nm = fmaxf(m_run, tm);
        if (__any(nm > m_run)) {   // wave-uniform rescale gate
            const float alpha = (m_run == -INFINITY) ? 0.f : __expf(m_run - nm);
            m_run = nm;
            l_run *= alpha;
            f32x4 av;
#pragma unroll
            for (int r = 0; r < 4; ++r) av[r] = __shfl(alpha, 4 * g + r);
#pragma unroll
            for (int i = 0; i < 8; ++i) o[i] *= av;
        }

        // exp + sum (in-register + 2 hops)
        float ps = 0.f;
#pragma unroll
        for (int r = 0; r < 4; ++r) {
            s0[r] = __expf(s0[r] - m_run);
            s1[r] = __expf(s1[r] - m_run);
            ps += s0[r] + s1[r];
        }
        ps += __shfl_xor(ps, 16);
        ps += __shfl_xor(ps, 32);
        l_run += ps;

        // P: pack 4 bf16 per half-tile, 2x ds_write_b64 into Pl[q][key]
        union { u16 u[4]; unsigned long long q; } p0, p1;
#pragma unroll
        for (int r = 0; r < 4; ++r) { p0.u[r] = f2bf(s0[r]); p1.u[r] = f2bf(s1[r]); }
        *(unsigned long long*)&Pl[wave][l15][4 * g]      = p0.q;
        *(unsigned long long*)&Pl[wave][l15][16 + 4 * g] = p1.q;

        // PV: P as A-operand [q=l15][key=g*8+j], V as B-operand from vt
        const bf16x8 pf = *(const bf16x8*)&Pl[wave][l15][g * 8];
#pragma unroll
        for (int i = 0; i < 8; ++i) {
            bf16x8 vf = *(const bf16x8*)(vbase +
                (size_t)(16 * i + l15) * S_ + k0 + g * 8);
            o[i] = __builtin_amdgcn_mfma_f32_16x16x32_bf16(pf, vf, o[i], 0, 0, 0);
        }
    }

    // epilogue: 1/l from softmax-domain -> O-domain, normalize, bf16 store
    const float invq = 1.0f / l_run;
    float inv[4];
#pragma unroll
    for (int r = 0; r < 4; ++r) inv[r] = __shfl(invq, 4 * g + r);
#pragma unroll
    for (int i = 0; i < 8; ++i)
#pragma unroll
        for (int r = 0; r < 4; ++r)
            out[(size_t)(b * S_ + q0 + 4 * g + r) * D_ +
                h * HD_ + 16 * i + l15] = f2bf(o[i][r] * inv[r]);
}

// ---------------------------------------------------------------------------
extern "C" void kernel_launch(void* const* d_in, const int* in_sizes, int n_in,
                              void* d_out, int out_size, void* d_ws, size_t ws_size,
                              hipStream_t stream) {
    const float* x        = (const float*)d_in[0];
    const unsigned char* mask = (const unsigned char*)d_in[1];
    const float* wq_down  = (const float*)d_in[2];
    const float* bq_down  = (const float*)d_in[3];
    const float* gq_ln    = (const float*)d_in[4];
    const float* bq_ln    = (const float*)d_in[5];
    const float* wq_up    = (const float*)d_in[6];
    const float* bq_up    = (const float*)d_in[7];
    const float* wkv_down = (const float*)d_in[8];
    const float* bkv_down = (const float*)d_in[9];
    const float* gkv_ln   = (const float*)d_in[10];
    const float* bkv_ln   = (const float*)d_in[11];
    const float* wkv_up   = (const float*)d_in[12];
    const float* bkv_up   = (const float*)d_in[13];
    const float* w_out    = (const float*)d_in[14];
    const float* b_out    = (const float*)d_in[15];
    float* out = (float*)d_out;

    // Workspace layout (byte offsets, MB). Total 90 MB.
    char* ws = (char*)d_ws;
    u16* x_bf      = (u16*)(ws);
    u16* vt        = (u16*)(ws);
    u16* kv_lat_bf = (u16*)(ws + (16u << 20));
    u16* attn_bf   = (u16*)(ws + (16u << 20));
    u16* q_lat_bf  = (u16*)(ws + (20u << 20));
    u16* wkvd_t    = (u16*)(ws + (24u << 20));
    u16* wqd_t     = (u16*)(ws + (26u << 20));
    u16* wkvu_t    = (u16*)(ws + (28u << 20));
    u16* wqu_t     = (u16*)(ws + (32u << 20));
    u16* wout_t    = (u16*)(ws + (34u << 20));
    u16* q_bf      = (u16*)(ws + (42u << 20));
    u16* kv_bf     = (u16*)(ws + (58u << 20));

    const int M = B_ * S_;  // 4096
    dim3 blk(256);

    // casts / transposes
    cast_bf16_kernel<<<(M * D_ / 4 + 255) / 256, blk, 0, stream>>>(x, x_bf, M * D_ / 4);
    cast_transpose_kernel<<<dim3(L_ / 64, D_ / 64), blk, 0, stream>>>(wq_down,  wqd_t,  D_, L_);
    cast_transpose_kernel<<<dim3(D_ / 64, L_ / 64), blk, 0, stream>>>(wq_up,    wqu_t,  L_, D_);
    cast_transpose_kernel<<<dim3(L_ / 64, D_ / 64), blk, 0, stream>>>(wkv_down, wkvd_t, D_, L_);
    cast_transpose_kernel<<<dim3(2 * D_ / 64, L_ / 64), blk, 0, stream>>>(wkv_up, wkvu_t, L_, 2 * D_);
    cast_transpose_kernel<<<dim3(D_ / 64, D_ / 64), blk, 0, stream>>>(w_out,    wout_t, D_, D_);

    // KV path
    gemm_mfma_kernel<u16><<<dim3(L_ / 128, M / 128), blk, 0, stream>>>(
        x_bf, wkvd_t, bkv_down, kv_lat_bf, M, L_, D_);
    layernorm512_bf16_kernel<<<M, blk, 0, stream>>>(kv_lat_bf, gkv_ln, bkv_ln);
    gemm_mfma_kernel<u16><<<dim3(2 * D_ / 128, M / 128), blk, 0, stream>>>(
        kv_lat_bf, wkvu_t, bkv_up, kv_bf, M, 2 * D_, L_);

    // Q path
    gemm_mfma_kernel<u16><<<dim3(L_ / 128, M / 128), blk, 0, stream>>>(
        x_bf, wqd_t, bq_down, q_lat_bf, M, L_, D_);
    layernorm512_bf16_kernel<<<M, blk, 0, stream>>>(q_lat_bf, gq_ln, bq_ln);
    gemm_mfma_kernel<u16><<<dim3(D_ / 128, M / 128), blk, 0, stream>>>(
        q_lat_bf, wqu_t, bq_up, q_bf, M, D_, L_);

    // V transpose (x_bf dead; vt overlays it)
    vtrans_kernel<<<dim3(S_ / 64, H_, B_), blk, 0, stream>>>(kv_bf, vt);

    // Flash attention v4 -> bf16 attn
    flash_attn_kernel<<<dim3((S_ / 64) * H_ * B_), blk, 0, stream>>>(
        q_bf, kv_bf, vt, mask, attn_bf);

    // Output projection (fp32 out)
    gemm_mfma_kernel<float><<<dim3(D_ / 128, M / 128), blk, 0, stream>>>(
        attn_bf, wout_t, b_out, out, M, D_, D_);
}